// Round 11
// baseline (394.588 us; speedup 1.0000x reference)
//
#include <hip/hip_runtime.h>

typedef float  f32x4_t  __attribute__((ext_vector_type(4)));
typedef __bf16 bf16x8_t __attribute__((ext_vector_type(8)));

#define BS   512
#define Mn   64
#define Kn   32
#define Fn   64
#define ROWS 2048   // Mn*Kn

// ws layout (floats)
#define WS_WZM  ((size_t)0)                       // 512*64*64  Wz_m
#define WS_WZK  ((size_t)512*4096)                // 512*32*64  Wz_k
#define WS_MNM  (WS_WZK + (size_t)512*2048)       // 512*64*64  msg_nm
#define WS_MNK4 (WS_MNM + (size_t)512*4096)       // 4*512*32*64 msg_nk partials

typedef const __attribute__((address_space(1))) void gas_void;
typedef __attribute__((address_space(3))) void las_void;

// ---------------- Kernel P: per-batch head matmuls -> ws ----------------
__global__ __launch_bounds__(256, 2) void gnn_pre(
    const float* __restrict__ z_m, const float* __restrict__ z_k,
    const float* __restrict__ Wm,  const float* __restrict__ Wk,
    float* __restrict__ ws)
{
    __shared__ __align__(16) float s[6144];
    float* s_zm = s;            // 4096
    float* s_zk = s + 4096;     // 2048
    const int tid = threadIdx.x, b = blockIdx.x;
    const int lane = tid & 63, wave = tid >> 6;
    const int f = lane, rg = wave;

    {
        const float4* a = (const float4*)(z_m + (size_t)b * 4096);
        for (int i = tid; i < 1024; i += 256) ((float4*)s_zm)[i] = a[i];
        const float4* c = (const float4*)(z_k + (size_t)b * 2048);
        for (int i = tid; i < 512; i += 256) ((float4*)s_zk)[i] = c[i];
    }
    __syncthreads();

    float am[16], ak[8];
    #pragma unroll
    for (int t = 0; t < 16; ++t) am[t] = 0.f;
    #pragma unroll
    for (int t = 0; t < 8; ++t) ak[t] = 0.f;

    for (int c0 = 0; c0 < 64; c0 += 16) {
        float wm[16], wk[16];
        #pragma unroll
        for (int cc = 0; cc < 16; ++cc) {
            wm[cc] = Wm[(c0 + cc) * 64 + f];
            wk[cc] = Wk[(c0 + cc) * 64 + f];
        }
        #pragma unroll
        for (int t = 0; t < 16; ++t) {
            const float* zp = s_zm + (rg + 4 * t) * 64 + c0;
            #pragma unroll
            for (int q = 0; q < 4; ++q) {
                float4 z = *(const float4*)(zp + q * 4);
                am[t] += z.x * wm[4*q] + z.y * wm[4*q+1] + z.z * wm[4*q+2] + z.w * wm[4*q+3];
            }
        }
        #pragma unroll
        for (int t = 0; t < 8; ++t) {
            const float* zp = s_zk + (rg + 4 * t) * 64 + c0;
            #pragma unroll
            for (int q = 0; q < 4; ++q) {
                float4 z = *(const float4*)(zp + q * 4);
                ak[t] += z.x * wk[4*q] + z.y * wk[4*q+1] + z.z * wk[4*q+2] + z.w * wk[4*q+3];
            }
        }
    }
    #pragma unroll
    for (int t = 0; t < 16; ++t)
        ws[WS_WZM + (size_t)b * 4096 + (rg + 4 * t) * 64 + f] = am[t];
    #pragma unroll
    for (int t = 0; t < 8; ++t)
        ws[WS_WZK + (size_t)b * 2048 + (rg + 4 * t) * 64 + f] = ak[t];
}

// ---------------- Kernel A (MODE/REPS) -----------------
// MODE 1 = no out0 stores (keepalive asm); MODE 3 = full, PLAIN stores.
// REPS amplifies the slab loop for rocprof visibility (probe only).
template <int MODE, int REPS>
__global__ __launch_bounds__(256, 3) void gnn_edges(
    const float* __restrict__ z_mk, const float* __restrict__ Wedge,
    float* __restrict__ out0, float* __restrict__ ws)
{
    __shared__ __align__(16) float s_all[12288];
    float* bufA  = s_all;            // 4096
    float* bufB  = s_all + 4096;     // 4096
    float* s_wzm = s_all + 8192;     // 1024
    float* s_mnm = s_all + 9216;     // 1024
    float* s_mnk = s_all + 10240;    // 2048

    const int tid  = threadIdx.x;
    const int bid  = blockIdx.x;
    const int b    = bid >> 2;
    const int mq   = bid & 3;
    const int lane = tid & 63;
    const int w    = tid >> 6;
    const int llo  = lane & 15;
    const int lhi  = lane >> 4;
    const int low  = llo, gr = lhi;
    const int p    = w & 1;

    for (int i = tid; i < 3072; i += 256) s_mnm[i] = 0.f;
    {
        const float4* src = (const float4*)(ws + WS_WZM + ((size_t)b * Mn + mq * 16) * Fn);
        ((float4*)s_wzm)[tid] = src[tid];
    }
    float wzk_r[4][4];
    {
        const float* wk = ws + WS_WZK + (size_t)b * Kn * Fn;
        #pragma unroll
        for (int j = 0; j < 4; ++j)
            #pragma unroll
            for (int n = 0; n < 4; ++n)
                wzk_r[j][n] = wk[(p * 16 + gr * 4 + j) * 64 + n * 16 + low];
    }
    bf16x8_t Bf[2][4];
    #pragma unroll
    for (int ks = 0; ks < 2; ++ks)
        #pragma unroll
        for (int n = 0; n < 4; ++n)
            #pragma unroll
            for (int i = 0; i < 8; ++i)
                Bf[ks][n][i] = (__bf16)Wedge[(ks * 32 + gr * 8 + i) * 64 + n * 16 + low];
    __syncthreads();

    const size_t blockrow0 = (size_t)b * ROWS + (size_t)mq * 512;
    const float* zsrc = z_mk + blockrow0 * 64;

    float nk[4][4];
    #pragma unroll
    for (int j = 0; j < 4; ++j)
        #pragma unroll
        for (int n = 0; n < 4; ++n) nk[j][n] = 0.f;

    auto stage = [&](float* buf, int s) {
        #pragma unroll
        for (int i = 0; i < 4; ++i) {
            const int R   = w * 16 + i * 4 + lhi;
            const int swz = llo ^ (i * 4 + lhi);
            const float* gp = zsrc + ((size_t)s * 64 + R) * 64 + swz * 4;
            float* lp = buf + (w * 4 + i) * 256;
            __builtin_amdgcn_global_load_lds((gas_void*)gp, (las_void*)lp, 16, 0, 0);
        }
    };

    #pragma unroll 1
    for (int rep = 0; rep < REPS; ++rep) {
        if (REPS > 1) {
            asm volatile("s_waitcnt vmcnt(0) lgkmcnt(0)" ::: "memory");
            __builtin_amdgcn_sched_barrier(0);
        }
        stage(bufA, 0);

        #pragma unroll 1
        for (int s = 0; s < 8; ++s) {
            float* bc = (s & 1) ? bufB : bufA;

            if (s < 7) {
                asm volatile("s_waitcnt lgkmcnt(0)" ::: "memory");
                __builtin_amdgcn_sched_barrier(0);
                stage((s & 1) ? bufA : bufB, s + 1);
            }
            if constexpr (MODE == 1) {
                if (s == 7) asm volatile("s_waitcnt vmcnt(0)" ::: "memory");
                else        asm volatile("s_waitcnt vmcnt(4)" ::: "memory");
            } else {
                if (s == 0 || s == 7) asm volatile("s_waitcnt vmcnt(4)" ::: "memory");
                else                  asm volatile("s_waitcnt vmcnt(8)" ::: "memory");
            }
            __builtin_amdgcn_sched_barrier(0);

            // A fragments from swizzled LDS
            bf16x8_t A[2];
            const int arow = (w * 16 + low) * 64;
            #pragma unroll
            for (int ks = 0; ks < 2; ++ks) {
                f32x4_t qa = *(const f32x4_t*)(bc + arow + (((ks * 8 + gr * 2 + 0) ^ low) << 2));
                f32x4_t qb = *(const f32x4_t*)(bc + arow + (((ks * 8 + gr * 2 + 1) ^ low) << 2));
                A[ks][0] = (__bf16)qa[0]; A[ks][1] = (__bf16)qa[1];
                A[ks][2] = (__bf16)qa[2]; A[ks][3] = (__bf16)qa[3];
                A[ks][4] = (__bf16)qb[0]; A[ks][5] = (__bf16)qb[1];
                A[ks][6] = (__bf16)qb[2]; A[ks][7] = (__bf16)qb[3];
            }

            f32x4_t acc[4];
            #pragma unroll
            for (int n = 0; n < 4; ++n) acc[n] = (f32x4_t){0.f, 0.f, 0.f, 0.f};
            #pragma unroll
            for (int ks = 0; ks < 2; ++ks)
                #pragma unroll
                for (int n = 0; n < 4; ++n)
                    acc[n] = __builtin_amdgcn_mfma_f32_16x16x32_bf16(A[ks], Bf[ks][n], acc[n], 0, 0, 0);

            const int ml = (s * 4 + w) >> 1;

            #pragma unroll
            for (int n = 0; n < 4; ++n) {
                const int fc = n * 16 + low;
                const float wmv = s_wzm[ml * 64 + fc];
                float snm = 0.f;
                #pragma unroll
                for (int j = 0; j < 4; ++j) {
                    float e = acc[n][j] + wmv + wzk_r[j][n];
                    e = e > 0.f ? e : 0.01f * e;
                    bc[(w * 16 + gr * 4 + j) * 64 + fc] = e;
                    nk[j][n] += e;
                    snm += e;
                }
                snm += __shfl_xor(snm, 16);
                snm += __shfl_xor(snm, 32);
                if (gr == 0) atomicAdd(&s_mnm[ml * 64 + fc], snm);
            }

            // storepass: own 16 rows, 4 x contiguous-1KB bursts per wave
            #pragma unroll
            for (int r = 0; r < 4; ++r) {
                const int lrow = w * 16 + lhi + 4 * r;
                f32x4_t v = *(const f32x4_t*)(bc + lrow * 64 + llo * 4);
                if constexpr (MODE == 1) {
                    asm volatile("" :: "v"(v));   // keep alive, no store
                } else {
                    *(f32x4_t*)(out0 + (blockrow0 + (size_t)s * 64 + lrow) * 64 + llo * 4) = v;
                }
            }
        }
    }

    #pragma unroll
    for (int j = 0; j < 4; ++j)
        #pragma unroll
        for (int n = 0; n < 4; ++n)
            atomicAdd(&s_mnk[(p * 16 + gr * 4 + j) * 64 + n * 16 + low], nk[j][n]);
    __syncthreads();

    float* dm = ws + WS_MNM + (size_t)b * 4096 + mq * 1024;
    for (int i = tid; i < 1024; i += 256) dm[i] = s_mnm[i];
    float* dk = ws + WS_MNK4 + ((size_t)mq * BS + b) * 2048;
    for (int i = tid; i < 2048; i += 256) dk[i] = s_mnk[i];
}

// ---------------- Kernel B: node updates -----------------
__global__ __launch_bounds__(256, 2) void gnn_nodes(
    const float* __restrict__ z_m, const float* __restrict__ z_k,
    const float* __restrict__ Wself_m, const float* __restrict__ Wself_k,
    const float* __restrict__ Wneigh_m, const float* __restrict__ Wneigh_k,
    const float* __restrict__ ws,
    float* __restrict__ out1, float* __restrict__ out2)
{
    __shared__ __align__(16) float s[12288];
    float* s_zm  = s;
    float* s_zk  = s + 4096;
    float* s_mnm = s + 6144;
    float* s_mnk = s + 10240;

    const int tid  = threadIdx.x;
    const int b    = blockIdx.x;
    const int lane = tid & 63;
    const int wave = tid >> 6;
    const int f    = lane;
    const int rg   = wave;

    {
        const float4* src = (const float4*)(z_m + (size_t)b * Mn * Fn);
        for (int i = tid; i < Mn * Fn / 4; i += 256) ((float4*)s_zm)[i] = src[i];
        const float4* src2 = (const float4*)(z_k + (size_t)b * Kn * Fn);
        for (int i = tid; i < Kn * Fn / 4; i += 256) ((float4*)s_zk)[i] = src2[i];
        const float4* srcm = (const float4*)(ws + WS_MNM + (size_t)b * Mn * Fn);
        for (int i = tid; i < Mn * Fn / 4; i += 256) ((float4*)s_mnm)[i] = srcm[i];
        const float* base = ws + WS_MNK4;
        const float* p0 = base + ((size_t)0 * BS + b) * (Kn * Fn);
        const float* p1 = base + ((size_t)1 * BS + b) * (Kn * Fn);
        const float* p2 = base + ((size_t)2 * BS + b) * (Kn * Fn);
        const float* p3 = base + ((size_t)3 * BS + b) * (Kn * Fn);
        for (int i = tid; i < Kn * Fn; i += 256) s_mnk[i] = p0[i] + p1[i] + p2[i] + p3[i];
    }
    __syncthreads();

    {
        float d[16], e[16];
        #pragma unroll
        for (int t = 0; t < 16; ++t) { d[t] = 0.f; e[t] = 0.f; }
        for (int c0 = 0; c0 < Fn; c0 += 16) {
            float wA[16], wB[16];
            #pragma unroll
            for (int cc = 0; cc < 16; ++cc) {
                wA[cc] = Wself_m[(c0 + cc) * Fn + f];
                wB[cc] = Wneigh_m[(c0 + cc) * Fn + f];
            }
            #pragma unroll
            for (int t = 0; t < 16; ++t) {
                const float* zp = s_zm + (rg + 4 * t) * Fn + c0;
                const float* mp = s_mnm + (rg + 4 * t) * Fn + c0;
                #pragma unroll
                for (int q = 0; q < 4; ++q) {
                    float4 z = *(const float4*)(zp + q * 4);
                    float4 m = *(const float4*)(mp + q * 4);
                    d[t] += z.x * wA[4*q] + z.y * wA[4*q+1] + z.z * wA[4*q+2] + z.w * wA[4*q+3];
                    e[t] += m.x * wB[4*q] + m.y * wB[4*q+1] + m.z * wB[4*q+2] + m.w * wB[4*q+3];
                }
            }
        }
        #pragma unroll
        for (int t = 0; t < 16; ++t) {
            float v = d[t] + e[t] * (1.f / 32.f);
            v = v > 0.f ? v : 0.01f * v;
            out1[(size_t)b * Mn * Fn + (rg + 4 * t) * Fn + f] = v;
        }
    }
    {
        float d[8], e[8];
        #pragma unroll
        for (int t = 0; t < 8; ++t) { d[t] = 0.f; e[t] = 0.f; }
        for (int c0 = 0; c0 < Fn; c0 += 16) {
            float wA[16], wB[16];
            #pragma unroll
            for (int cc = 0; cc < 16; ++cc) {
                wA[cc] = Wself_k[(c0 + cc) * Fn + f];
                wB[cc] = Wneigh_k[(c0 + cc) * Fn + f];
            }
            #pragma unroll
            for (int t = 0; t < 8; ++t) {
                const float* zp = s_zk + (rg + 4 * t) * Fn + c0;
                const float* mp = s_mnk + (rg + 4 * t) * Fn + c0;
                #pragma unroll
                for (int q = 0; q < 4; ++q) {
                    float4 z = *(const float4*)(zp + q * 4);
                    float4 m = *(const float4*)(mp + q * 4);
                    d[t] += z.x * wA[4*q] + z.y * wA[4*q+1] + z.z * wA[4*q+2] + z.w * wA[4*q+3];
                    e[t] += m.x * wB[4*q] + m.y * wB[4*q+1] + m.z * wB[4*q+2] + m.w * wB[4*q+3];
                }
            }
        }
        #pragma unroll
        for (int t = 0; t < 8; ++t) {
            float v = d[t] + e[t] * (1.f / 64.f);
            v = v > 0.f ? v : 0.01f * v;
            out2[(size_t)b * Kn * Fn + (rg + 4 * t) * Fn + f] = v;
        }
    }
}

extern "C" void kernel_launch(void* const* d_in, const int* in_sizes, int n_in,
                              void* d_out, int out_size, void* d_ws, size_t ws_size,
                              hipStream_t stream) {
    const float* z_mk     = (const float*)d_in[0];
    const float* z_m      = (const float*)d_in[1];
    const float* z_k      = (const float*)d_in[2];
    const float* Wedge    = (const float*)d_in[3];
    const float* Wm       = (const float*)d_in[4];
    const float* Wk       = (const float*)d_in[5];
    const float* Wself_m  = (const float*)d_in[6];
    const float* Wself_k  = (const float*)d_in[7];
    const float* Wneigh_m = (const float*)d_in[8];
    const float* Wneigh_k = (const float*)d_in[9];

    float* out0 = (float*)d_out;                       // (512, 2048, 64)
    float* out1 = out0 + (size_t)BS * ROWS * Fn;       // (512, 64, 64)
    float* out2 = out1 + (size_t)BS * Mn * Fn;         // (512, 32, 64)
    float* ws   = (float*)d_ws;

    gnn_pre<<<BS, 256, 0, stream>>>(z_m, z_k, Wm, Wk, ws);
    // probe: NOSTORE x3 (amplified -> visible in rocprof top-5 if e1 > ~53us)
    gnn_edges<1, 3><<<BS * 4, 256, 0, stream>>>(z_mk, Wedge, out0, ws);
    // real: full pipeline with PLAIN stores (NT-retirement fix attempt), last
    gnn_edges<3, 1><<<BS * 4, 256, 0, stream>>>(z_mk, Wedge, out0, ws);
    gnn_nodes<<<BS, 256, 0, stream>>>(z_m, z_k, Wself_m, Wself_k,
                                      Wneigh_m, Wneigh_k, ws, out1, out2);
}

// Round 13
// 196.969 us; speedup vs baseline: 2.0033x; 2.0033x over previous
//
#include <hip/hip_runtime.h>

typedef float  f32x4_t  __attribute__((ext_vector_type(4)));
typedef __bf16 bf16x8_t __attribute__((ext_vector_type(8)));

#define BS   512
#define Mn   64
#define Kn   32
#define Fn   64
#define ROWS 2048   // Mn*Kn

// ws layout (floats)
#define WS_WZM  ((size_t)0)                       // 512*64*64  Wz_m
#define WS_WZK  ((size_t)512*4096)                // 512*32*64  Wz_k
#define WS_MNM  (WS_WZK + (size_t)512*2048)       // 512*64*64  msg_nm
#define WS_MNK4 (WS_MNM + (size_t)512*4096)       // 4*512*32*64 msg_nk partials

typedef const __attribute__((address_space(1))) void gas_void;
typedef __attribute__((address_space(3))) void las_void;

// ---------------- Kernel P: per-batch head matmuls -> ws ----------------
__global__ __launch_bounds__(256, 2) void gnn_pre(
    const float* __restrict__ z_m, const float* __restrict__ z_k,
    const float* __restrict__ Wm,  const float* __restrict__ Wk,
    float* __restrict__ ws)
{
    __shared__ __align__(16) float s[6144];
    float* s_zm = s;            // 4096
    float* s_zk = s + 4096;     // 2048
    const int tid = threadIdx.x, b = blockIdx.x;
    const int lane = tid & 63, wave = tid >> 6;
    const int f = lane, rg = wave;

    {
        const float4* a = (const float4*)(z_m + (size_t)b * 4096);
        for (int i = tid; i < 1024; i += 256) ((float4*)s_zm)[i] = a[i];
        const float4* c = (const float4*)(z_k + (size_t)b * 2048);
        for (int i = tid; i < 512; i += 256) ((float4*)s_zk)[i] = c[i];
    }
    __syncthreads();

    float am[16], ak[8];
    #pragma unroll
    for (int t = 0; t < 16; ++t) am[t] = 0.f;
    #pragma unroll
    for (int t = 0; t < 8; ++t) ak[t] = 0.f;

    for (int c0 = 0; c0 < 64; c0 += 16) {
        float wm[16], wk[16];
        #pragma unroll
        for (int cc = 0; cc < 16; ++cc) {
            wm[cc] = Wm[(c0 + cc) * 64 + f];
            wk[cc] = Wk[(c0 + cc) * 64 + f];
        }
        #pragma unroll
        for (int t = 0; t < 16; ++t) {
            const float* zp = s_zm + (rg + 4 * t) * 64 + c0;
            #pragma unroll
            for (int q = 0; q < 4; ++q) {
                float4 z = *(const float4*)(zp + q * 4);
                am[t] += z.x * wm[4*q] + z.y * wm[4*q+1] + z.z * wm[4*q+2] + z.w * wm[4*q+3];
            }
        }
        #pragma unroll
        for (int t = 0; t < 8; ++t) {
            const float* zp = s_zk + (rg + 4 * t) * 64 + c0;
            #pragma unroll
            for (int q = 0; q < 4; ++q) {
                float4 z = *(const float4*)(zp + q * 4);
                ak[t] += z.x * wk[4*q] + z.y * wk[4*q+1] + z.z * wk[4*q+2] + z.w * wk[4*q+3];
            }
        }
    }
    #pragma unroll
    for (int t = 0; t < 16; ++t)
        ws[WS_WZM + (size_t)b * 4096 + (rg + 4 * t) * 64 + f] = am[t];
    #pragma unroll
    for (int t = 0; t < 8; ++t)
        ws[WS_WZK + (size_t)b * 2048 + (rg + 4 * t) * 64 + f] = ak[t];
}

// ---------------- Kernel A: edges + messages -----------------
// grid 2048 = 512 batches x 4 m-quarters; 256 threads (4 waves).
// 40KB LDS (s_mnk aliased onto bufA post-loop) -> 4 blocks/CU (160KB) =
// 16 waves/CU. Plain stores (NT poisoned every in-order vmcnt wait, R11).
// R12 lesson: the slab loop is barrier-free, so waves drift -- MUST
// __syncthreads() before zeroing the aliased bufA (wave 0 was memsetting
// it while wave 3 still read its s=6 A-fragments from it).
__global__ __launch_bounds__(256, 3) void gnn_edges(
    const float* __restrict__ z_mk, const float* __restrict__ Wedge,
    float* __restrict__ out0, float* __restrict__ ws)
{
    __shared__ __align__(16) float s_all[10240];   // 40KB
    float* bufA  = s_all;            // 4096 floats (16KB)
    float* bufB  = s_all + 4096;     // 4096
    float* s_wzm = s_all + 8192;     // 1024
    float* s_mnm = s_all + 9216;     // 1024
    float* s_mnk = bufA;             // post-loop alias (after barrier!)

    const int tid  = threadIdx.x;
    const int bid  = blockIdx.x;
    const int b    = bid >> 2;
    const int mq   = bid & 3;
    const int lane = tid & 63;
    const int w    = tid >> 6;
    const int llo  = lane & 15;
    const int lhi  = lane >> 4;
    const int low  = llo, gr = lhi;
    const int p    = w & 1;

    for (int i = tid; i < 1024; i += 256) s_mnm[i] = 0.f;
    {
        const float4* src = (const float4*)(ws + WS_WZM + ((size_t)b * Mn + mq * 16) * Fn);
        ((float4*)s_wzm)[tid] = src[tid];
    }
    float wzk_r[4][4];
    {
        const float* wk = ws + WS_WZK + (size_t)b * Kn * Fn;
        #pragma unroll
        for (int j = 0; j < 4; ++j)
            #pragma unroll
            for (int n = 0; n < 4; ++n)
                wzk_r[j][n] = wk[(p * 16 + gr * 4 + j) * 64 + n * 16 + low];
    }
    bf16x8_t Bf[2][4];
    #pragma unroll
    for (int ks = 0; ks < 2; ++ks)
        #pragma unroll
        for (int n = 0; n < 4; ++n)
            #pragma unroll
            for (int i = 0; i < 8; ++i)
                Bf[ks][n][i] = (__bf16)Wedge[(ks * 32 + gr * 8 + i) * 64 + n * 16 + low];
    __syncthreads();

    const size_t blockrow0 = (size_t)b * ROWS + (size_t)mq * 512;
    const float* zsrc = z_mk + blockrow0 * 64;

    float nk[4][4];
    #pragma unroll
    for (int j = 0; j < 4; ++j)
        #pragma unroll
        for (int n = 0; n < 4; ++n) nk[j][n] = 0.f;

    auto stage = [&](float* buf, int s) {
        #pragma unroll
        for (int i = 0; i < 4; ++i) {
            const int R   = w * 16 + i * 4 + lhi;
            const int swz = llo ^ (i * 4 + lhi);
            const float* gp = zsrc + ((size_t)s * 64 + R) * 64 + swz * 4;
            float* lp = buf + (w * 4 + i) * 256;
            __builtin_amdgcn_global_load_lds((gas_void*)gp, (las_void*)lp, 16, 0, 0);
        }
    };

    stage(bufA, 0);

    #pragma unroll 1
    for (int s = 0; s < 8; ++s) {
        float* bc = (s & 1) ? bufB : bufA;

        if (s < 7) {
            asm volatile("s_waitcnt lgkmcnt(0)" ::: "memory");
            __builtin_amdgcn_sched_barrier(0);
            stage((s & 1) ? bufA : bufB, s + 1);
        }
        if (s == 0 || s == 7) asm volatile("s_waitcnt vmcnt(4)" ::: "memory");
        else                  asm volatile("s_waitcnt vmcnt(8)" ::: "memory");
        __builtin_amdgcn_sched_barrier(0);

        // A fragments from swizzled LDS (conflict-free b128 reads)
        bf16x8_t A[2];
        const int arow = (w * 16 + low) * 64;
        #pragma unroll
        for (int ks = 0; ks < 2; ++ks) {
            f32x4_t qa = *(const f32x4_t*)(bc + arow + (((ks * 8 + gr * 2 + 0) ^ low) << 2));
            f32x4_t qb = *(const f32x4_t*)(bc + arow + (((ks * 8 + gr * 2 + 1) ^ low) << 2));
            A[ks][0] = (__bf16)qa[0]; A[ks][1] = (__bf16)qa[1];
            A[ks][2] = (__bf16)qa[2]; A[ks][3] = (__bf16)qa[3];
            A[ks][4] = (__bf16)qb[0]; A[ks][5] = (__bf16)qb[1];
            A[ks][6] = (__bf16)qb[2]; A[ks][7] = (__bf16)qb[3];
        }

        f32x4_t acc[4];
        #pragma unroll
        for (int n = 0; n < 4; ++n) acc[n] = (f32x4_t){0.f, 0.f, 0.f, 0.f};
        #pragma unroll
        for (int ks = 0; ks < 2; ++ks)
            #pragma unroll
            for (int n = 0; n < 4; ++n)
                acc[n] = __builtin_amdgcn_mfma_f32_16x16x32_bf16(A[ks], Bf[ks][n], acc[n], 0, 0, 0);

        const int ml = (s * 4 + w) >> 1;

        // epilogue: e -> LDS transpose (own region, now dead) + messages
        #pragma unroll
        for (int n = 0; n < 4; ++n) {
            const int fc = n * 16 + low;
            const float wmv = s_wzm[ml * 64 + fc];
            float snm = 0.f;
            #pragma unroll
            for (int j = 0; j < 4; ++j) {
                float e = acc[n][j] + wmv + wzk_r[j][n];
                e = e > 0.f ? e : 0.01f * e;
                bc[(w * 16 + gr * 4 + j) * 64 + fc] = e;
                nk[j][n] += e;
                snm += e;
            }
            snm += __shfl_xor(snm, 16);
            snm += __shfl_xor(snm, 32);
            if (gr == 0) atomicAdd(&s_mnm[ml * 64 + fc], snm);
        }

        // storepass: own 16 rows, 4 x contiguous-1KB plain-store bursts
        #pragma unroll
        for (int r = 0; r < 4; ++r) {
            const int lrow = w * 16 + lhi + 4 * r;
            f32x4_t v = *(const f32x4_t*)(bc + lrow * 64 + llo * 4);
            *(f32x4_t*)(out0 + (blockrow0 + (size_t)s * 64 + lrow) * 64 + llo * 4) = v;
        }
    }

    // R12 fix: waves drift in the barrier-free loop -- sync before reusing
    // bufA as the msg_nk reduction buffer.
    __syncthreads();
    for (int i = tid; i < 2048; i += 256) s_mnk[i] = 0.f;
    __syncthreads();
    #pragma unroll
    for (int j = 0; j < 4; ++j)
        #pragma unroll
        for (int n = 0; n < 4; ++n)
            atomicAdd(&s_mnk[(p * 16 + gr * 4 + j) * 64 + n * 16 + low], nk[j][n]);
    __syncthreads();

    float* dm = ws + WS_MNM + (size_t)b * 4096 + mq * 1024;
    for (int i = tid; i < 1024; i += 256) dm[i] = s_mnm[i];
    float* dk = ws + WS_MNK4 + ((size_t)mq * BS + b) * 2048;
    for (int i = tid; i < 2048; i += 256) dk[i] = s_mnk[i];
}

// ---------------- Kernel B: node updates -----------------
__global__ __launch_bounds__(256, 2) void gnn_nodes(
    const float* __restrict__ z_m, const float* __restrict__ z_k,
    const float* __restrict__ Wself_m, const float* __restrict__ Wself_k,
    const float* __restrict__ Wneigh_m, const float* __restrict__ Wneigh_k,
    const float* __restrict__ ws,
    float* __restrict__ out1, float* __restrict__ out2)
{
    __shared__ __align__(16) float s[12288];
    float* s_zm  = s;
    float* s_zk  = s + 4096;
    float* s_mnm = s + 6144;
    float* s_mnk = s + 10240;

    const int tid  = threadIdx.x;
    const int b    = blockIdx.x;
    const int lane = tid & 63;
    const int wave = tid >> 6;
    const int f    = lane;
    const int rg   = wave;

    {
        const float4* src = (const float4*)(z_m + (size_t)b * Mn * Fn);
        for (int i = tid; i < Mn * Fn / 4; i += 256) ((float4*)s_zm)[i] = src[i];
        const float4* src2 = (const float4*)(z_k + (size_t)b * Kn * Fn);
        for (int i = tid; i < Kn * Fn / 4; i += 256) ((float4*)s_zk)[i] = src2[i];
        const float4* srcm = (const float4*)(ws + WS_MNM + (size_t)b * Mn * Fn);
        for (int i = tid; i < Mn * Fn / 4; i += 256) ((float4*)s_mnm)[i] = srcm[i];
        const float* base = ws + WS_MNK4;
        const float* p0 = base + ((size_t)0 * BS + b) * (Kn * Fn);
        const float* p1 = base + ((size_t)1 * BS + b) * (Kn * Fn);
        const float* p2 = base + ((size_t)2 * BS + b) * (Kn * Fn);
        const float* p3 = base + ((size_t)3 * BS + b) * (Kn * Fn);
        for (int i = tid; i < Kn * Fn; i += 256) s_mnk[i] = p0[i] + p1[i] + p2[i] + p3[i];
    }
    __syncthreads();

    {
        float d[16], e[16];
        #pragma unroll
        for (int t = 0; t < 16; ++t) { d[t] = 0.f; e[t] = 0.f; }
        for (int c0 = 0; c0 < Fn; c0 += 16) {
            float wA[16], wB[16];
            #pragma unroll
            for (int cc = 0; cc < 16; ++cc) {
                wA[cc] = Wself_m[(c0 + cc) * Fn + f];
                wB[cc] = Wneigh_m[(c0 + cc) * Fn + f];
            }
            #pragma unroll
            for (int t = 0; t < 16; ++t) {
                const float* zp = s_zm + (rg + 4 * t) * Fn + c0;
                const float* mp = s_mnm + (rg + 4 * t) * Fn + c0;
                #pragma unroll
                for (int q = 0; q < 4; ++q) {
                    float4 z = *(const float4*)(zp + q * 4);
                    float4 m = *(const float4*)(mp + q * 4);
                    d[t] += z.x * wA[4*q] + z.y * wA[4*q+1] + z.z * wA[4*q+2] + z.w * wA[4*q+3];
                    e[t] += m.x * wB[4*q] + m.y * wB[4*q+1] + m.z * wB[4*q+2] + m.w * wB[4*q+3];
                }
            }
        }
        #pragma unroll
        for (int t = 0; t < 16; ++t) {
            float v = d[t] + e[t] * (1.f / 32.f);
            v = v > 0.f ? v : 0.01f * v;
            out1[(size_t)b * Mn * Fn + (rg + 4 * t) * Fn + f] = v;
        }
    }
    {
        float d[8], e[8];
        #pragma unroll
        for (int t = 0; t < 8; ++t) { d[t] = 0.f; e[t] = 0.f; }
        for (int c0 = 0; c0 < Fn; c0 += 16) {
            float wA[16], wB[16];
            #pragma unroll
            for (int cc = 0; cc < 16; ++cc) {
                wA[cc] = Wself_k[(c0 + cc) * Fn + f];
                wB[cc] = Wneigh_k[(c0 + cc) * Fn + f];
            }
            #pragma unroll
            for (int t = 0; t < 8; ++t) {
                const float* zp = s_zk + (rg + 4 * t) * Fn + c0;
                const float* mp = s_mnk + (rg + 4 * t) * Fn + c0;
                #pragma unroll
                for (int q = 0; q < 4; ++q) {
                    float4 z = *(const float4*)(zp + q * 4);
                    float4 m = *(const float4*)(mp + q * 4);
                    d[t] += z.x * wA[4*q] + z.y * wA[4*q+1] + z.z * wA[4*q+2] + z.w * wA[4*q+3];
                    e[t] += m.x * wB[4*q] + m.y * wB[4*q+1] + m.z * wB[4*q+2] + m.w * wB[4*q+3];
                }
            }
        }
        #pragma unroll
        for (int t = 0; t < 8; ++t) {
            float v = d[t] + e[t] * (1.f / 64.f);
            v = v > 0.f ? v : 0.01f * v;
            out2[(size_t)b * Kn * Fn + (rg + 4 * t) * Fn + f] = v;
        }
    }
}

extern "C" void kernel_launch(void* const* d_in, const int* in_sizes, int n_in,
                              void* d_out, int out_size, void* d_ws, size_t ws_size,
                              hipStream_t stream) {
    const float* z_mk     = (const float*)d_in[0];
    const float* z_m      = (const float*)d_in[1];
    const float* z_k      = (const float*)d_in[2];
    const float* Wedge    = (const float*)d_in[3];
    const float* Wm       = (const float*)d_in[4];
    const float* Wk       = (const float*)d_in[5];
    const float* Wself_m  = (const float*)d_in[6];
    const float* Wself_k  = (const float*)d_in[7];
    const float* Wneigh_m = (const float*)d_in[8];
    const float* Wneigh_k = (const float*)d_in[9];

    float* out0 = (float*)d_out;                       // (512, 2048, 64)
    float* out1 = out0 + (size_t)BS * ROWS * Fn;       // (512, 64, 64)
    float* out2 = out1 + (size_t)BS * Mn * Fn;         // (512, 32, 64)
    float* ws   = (float*)d_ws;

    gnn_pre<<<BS, 256, 0, stream>>>(z_m, z_k, Wm, Wk, ws);
    gnn_edges<<<BS * 4, 256, 0, stream>>>(z_mk, Wedge, out0, ws);
    gnn_nodes<<<BS, 256, 0, stream>>>(z_m, z_k, Wself_m, Wself_k,
                                      Wneigh_m, Wneigh_k, ws, out1, out2);
}